// Round 14
// baseline (373.059 us; speedup 1.0000x reference)
//
#include <hip/hip_runtime.h>
#include <hip/hip_bf16.h>
#include <math.h>

#define H  128
#define NN 50000
#define EE 800000
#define GG 256
#define NB 196          // ceil(NN/256); NB*256 = 50176
#define NWG_E 12500     // EE/64 edge-kernel blocks

#define K3 256
#define NSTRIDE 264     // node x-tile LDS row stride
#define ESTRIDE 136     // hidden tile LDS row stride
#define PSTRIDE 136     // p12 staging stride

typedef __attribute__((ext_vector_type(8))) short bhalf8;
typedef __attribute__((ext_vector_type(4))) float f32x4;

__device__ __forceinline__ float silu_f(float x) {
    return x * __builtin_amdgcn_rcpf(1.0f + exp2f(x * -1.442695041f));
}

// fp32 -> bf16 RTNE via library cast: compiler emits v_cvt_pk_bf16_f32 for pairs
__device__ __forceinline__ unsigned short f2bf(float x) {
    __hip_bfloat16 h = __float2bfloat16(x);
    return *reinterpret_cast<unsigned short*>(&h);
}

// bf16 bits -> fp32
__device__ __forceinline__ float bf2f(unsigned short s) {
    return __uint_as_float(((unsigned int)s) << 16);
}

// ---- fast zero (runtime memset node fills at ~100 GB/s; this runs full-grid) ----
__global__ void zero_kernel(uint4* __restrict__ p, int n16) {
    uint4 z; z.x = z.y = z.z = z.w = 0;
    for (int i = blockIdx.x * blockDim.x + threadIdx.x; i < n16; i += gridDim.x * blockDim.x)
        p[i] = z;
}

// ---- merged prep kernel: W2T/W4T/W3T/W12T/Qb + degree count ----
__global__ __launch_bounds__(256) void prep_kernel(
    const float* __restrict__ W1, const float* __restrict__ b1,
    const float* __restrict__ W2, const float* __restrict__ W3,
    const float* __restrict__ W4, const float* __restrict__ lat,
    const int* __restrict__ ei,
    unsigned short* __restrict__ W12T, unsigned short* __restrict__ W2T,
    unsigned short* __restrict__ W3T, unsigned short* __restrict__ W4T,
    unsigned short* __restrict__ Qb, int* __restrict__ cnt_i)
{
    int bid = blockIdx.x, tid = threadIdx.x;
    if (bid < 64) {
        int c = bid * 2 + (tid >> 7), k = tid & 127;
        W2T[(size_t)c * H + k] = f2bf(W2[(size_t)k * H + c]);
    } else if (bid < 128) {
        int c = (bid - 64) * 2 + (tid >> 7), k = tid & 127;
        W4T[(size_t)c * H + k] = f2bf(W4[(size_t)k * H + c]);
    } else if (bid < 256) {
        int c = bid - 128, k = tid;
        W3T[(size_t)c * K3 + k] = f2bf(W3[(size_t)k * H + c]);
    } else if (bid < 384) {
        int j = (bid - 256) * 2 + (tid >> 7), k = tid & 127;
        float v = (j < 128) ? W1[(size_t)k * H + j] : W1[(size_t)(128 + k) * H + (j - 128)];
        W12T[(size_t)j * H + k] = f2bf(v);
    } else if (bid < 512) {
        int g = (bid - 384) * 2 + (tid >> 7), c = tid & 127;
        const float* L = lat + g * 9;
        float q = b1[c];
        #pragma unroll
        for (int i = 0; i < 3; ++i)
            #pragma unroll
            for (int k = 0; k < 3; ++k) {
                float ip = L[i*3+0]*L[k*3+0] + L[i*3+1]*L[k*3+1] + L[i*3+2]*L[k*3+2];
                q += ip * W1[(size_t)(256 + i * 3 + k) * H + c];
            }
        Qb[(size_t)g * H + c] = f2bf(q);
    } else {
        int e = (bid - 512) * 256 + tid;
        if (e < EE) atomicAdd(&cnt_i[ei[EE + e]], 1);
    }
}

// P12[n][0:128] = nf[n] @ W1a ; P12[n][128:256] = nf[n] @ W1b  (bf16 out)
__global__ __launch_bounds__(256) void p12_kernel(
    const float* __restrict__ nf, const unsigned short* __restrict__ W12T,
    unsigned short* __restrict__ P12)
{
    __shared__ unsigned short x_lds[64 * PSTRIDE];
    int tid = threadIdx.x;
    int nb = blockIdx.x * 64;

    #pragma unroll
    for (int p = 0; p < 8; ++p) {
        int idx = p * 256 + tid;
        int n = idx >> 5, c = idx & 31;
        int node = nb + n; if (node >= NN) node = NN - 1;
        float4 v = *(const float4*)(nf + (size_t)node * H + c * 4);
        ushort4 o;
        o.x = f2bf(v.x); o.y = f2bf(v.y); o.z = f2bf(v.z); o.w = f2bf(v.w);
        *(ushort4*)(&x_lds[n * PSTRIDE + c * 4]) = o;
    }
    __syncthreads();

    int wid = tid >> 6, lane = tid & 63;
    int wr = wid & 1, wc = wid >> 1;       // rows wr*32.., cols wc*128..
    int lr = lane & 15, lk = lane >> 4;

    f32x4 acc[2][8];
    #pragma unroll
    for (int m = 0; m < 2; ++m)
        #pragma unroll
        for (int n = 0; n < 8; ++n) acc[m][n] = (f32x4){0.f, 0.f, 0.f, 0.f};

    #pragma unroll
    for (int ks = 0; ks < 4; ++ks) {
        bhalf8 a[2], b[8];
        #pragma unroll
        for (int m = 0; m < 2; ++m)
            a[m] = *(const bhalf8*)(&x_lds[(wr * 32 + m * 16 + lr) * PSTRIDE + ks * 32 + lk * 8]);
        #pragma unroll
        for (int n = 0; n < 8; ++n)
            b[n] = *(const bhalf8*)(W12T + (size_t)(wc * 128 + n * 16 + lr) * H + ks * 32 + lk * 8);
        #pragma unroll
        for (int m = 0; m < 2; ++m)
            #pragma unroll
            for (int n = 0; n < 8; ++n)
                acc[m][n] = __builtin_amdgcn_mfma_f32_16x16x32_bf16(a[m], b[n], acc[m][n], 0, 0, 0);
    }

    #pragma unroll
    for (int m = 0; m < 2; ++m)
        #pragma unroll
        for (int n = 0; n < 8; ++n)
            #pragma unroll
            for (int j = 0; j < 4; ++j) {
                int row = wr * 32 + m * 16 + lk * 4 + j;
                int col = wc * 128 + n * 16 + lr;
                int node = nb + row;
                if (node < NN) P12[(size_t)node * 256 + col] = f2bf(acc[m][n][j]);
            }
}

// ---- single-kernel exclusive scan over cnt_i[0..NB*256) -> row_start ----
// 1024 threads, thread t owns 49 consecutive elements (1024*49 = 50176)
__global__ __launch_bounds__(1024) void scan_kernel(
    const int* __restrict__ cnt_i, int* __restrict__ row_start)
{
    __shared__ int tot[1024];
    int t = threadIdx.x;
    int base = t * 49;
    int s = 0;
    for (int i = 0; i < 49; ++i) s += cnt_i[base + i];
    tot[t] = s;
    __syncthreads();
    for (int st = 1; st < 1024; st <<= 1) {
        int u = (t >= st) ? tot[t - st] : 0;
        __syncthreads();
        tot[t] += u;
        __syncthreads();
    }
    int run = (t > 0) ? tot[t - 1] : 0;
    for (int i = 0; i < 49; ++i) {
        int c = cnt_i[base + i];
        row_start[base + i] = run;
        run += c;
    }
}

__global__ void scatter_kernel(const int* __restrict__ ei, const int* __restrict__ row_start,
                               int* __restrict__ fill, int* __restrict__ eidx) {
    int e = blockIdx.x * blockDim.x + threadIdx.x;
    if (e < EE) {
        int d = ei[EE + e];
        int pos = row_start[d] + atomicAdd(&fill[d], 1);
        eidx[pos] = e;
    }
}

// ---- edge kernel v10: 64-edge tiles, XCD-swizzled, cvt_pk-friendly converts ----
__global__ __launch_bounds__(256, 5) void edge_kernel(
    const unsigned short* __restrict__ P12, const unsigned short* __restrict__ Qb,
    const float* __restrict__ fdg, const float* __restrict__ W1fd,
    const unsigned short* __restrict__ W2T, const float* __restrict__ b2,
    const int* __restrict__ ei, const int* __restrict__ e2g,
    const int* __restrict__ eidx,
    float* __restrict__ out_edge, float* __restrict__ sums)
{
    __shared__ unsigned short e1[64 * ESTRIDE];   // 17.4 KB; reused as out-tile (bf16)
    __shared__ int sE[64], sSrc[64], sDst[64], sG[64];
    __shared__ float sFd[64 * 3];

    int tid = threadIdx.x;

    // bijective XCD swizzle: nwg = 12500 = 8*1562 + 4; xcd<4 get 1563 blocks
    int xcd = blockIdx.x & 7, li = blockIdx.x >> 3;
    int bswz = (xcd < 4) ? (xcd * 1563 + li) : (4 * 1563 + (xcd - 4) * 1562 + li);
    int eb = bswz * 64;

    if (tid < 64) sE[tid] = eidx[eb + tid];
    __syncthreads();
    if (tid < 64) {
        sSrc[tid] = ei[sE[tid]];
    } else if (tid < 128) {
        sDst[tid - 64] = ei[EE + sE[tid - 64]];
    } else if (tid < 192) {
        sG[tid - 128] = e2g[sE[tid - 128]];
    } else {
        int r = tid - 192;
        int e = sE[r];
        sFd[r * 3 + 0] = fdg[(size_t)e * 3 + 0];
        sFd[r * 3 + 1] = fdg[(size_t)e * 3 + 1];
        sFd[r * 3 + 2] = fdg[(size_t)e * 3 + 2];
    }
    __syncthreads();

    int c = tid & 15;
    // per-lane W1_fd columns (3 rows x 8 cols), L1-cached
    float4 wf[3][2];
    #pragma unroll
    for (int k = 0; k < 3; ++k)
        #pragma unroll
        for (int h = 0; h < 2; ++h)
            wf[k][h] = *(const float4*)(W1fd + k * H + c * 8 + h * 4);

    // ---- prefetch all P12 gathers (8 independent 16B loads in flight) ----
    uint4 P1v[4], P2v[4];
    #pragma unroll
    for (int p = 0; p < 4; ++p) {
        int r = p * 16 + (tid >> 4);
        P1v[p] = *(const uint4*)(P12 + (size_t)sSrc[r] * 256 + c * 8);
        P2v[p] = *(const uint4*)(P12 + (size_t)sDst[r] * 256 + 128 + c * 8);
    }

    // ---- build e1[64][128] (bf16): 4 rows per thread ----
    #pragma unroll
    for (int p = 0; p < 4; ++p) {
        int r = p * 16 + (tid >> 4);
        int g = sG[r];
        bhalf8 p1 = *(const bhalf8*)(&P1v[p]);
        bhalf8 p2 = *(const bhalf8*)(&P2v[p]);
        bhalf8 qv = *(const bhalf8*)(Qb + (size_t)g * H + c * 8);
        float f0 = sFd[r * 3 + 0], f1 = sFd[r * 3 + 1], f2v = sFd[r * 3 + 2];
        ushort4 pk[2];
        #pragma unroll
        for (int jj = 0; jj < 8; ++jj) {
            const float* wfp = (const float*)&wf[0][0];
            float v = bf2f((unsigned short)p1[jj]) + bf2f((unsigned short)p2[jj])
                    + bf2f((unsigned short)qv[jj])
                    + f0 * wfp[jj] + f1 * wfp[8 + jj] + f2v * wfp[16 + jj];
            ((unsigned short*)pk)[jj] = f2bf(silu_f(v));
        }
        *(ushort4*)(&e1[r * ESTRIDE + c * 8]) = pk[0];
        *(ushort4*)(&e1[r * ESTRIDE + c * 8 + 4]) = pk[1];
    }
    __syncthreads();

    // ---- mm2: 4 waves, each 32 rows x 64 cols ----
    int wid = tid >> 6, lane = tid & 63;
    int wr = wid >> 1, wcc = wid & 1;   // rows wr*32.., cols wcc*64..
    int lr = lane & 15, lk = lane >> 4;

    f32x4 acc2[4][2];
    #pragma unroll
    for (int a = 0; a < 4; ++a)
        #pragma unroll
        for (int b = 0; b < 2; ++b) acc2[a][b] = (f32x4){0.f, 0.f, 0.f, 0.f};

    #pragma unroll
    for (int ks = 0; ks < 4; ++ks) {
        bhalf8 wa[4], xb[2];
        #pragma unroll
        for (int ai = 0; ai < 4; ++ai)
            wa[ai] = *(const bhalf8*)(W2T + (size_t)(wcc * 64 + ai * 16 + lr) * H + ks * 32 + lk * 8);
        #pragma unroll
        for (int bj = 0; bj < 2; ++bj)
            xb[bj] = *(const bhalf8*)(&e1[(wr * 32 + bj * 16 + lr) * ESTRIDE + ks * 32 + lk * 8]);
        #pragma unroll
        for (int ai = 0; ai < 4; ++ai)
            #pragma unroll
            for (int bj = 0; bj < 2; ++bj)
                acc2[ai][bj] = __builtin_amdgcn_mfma_f32_16x16x32_bf16(wa[ai], xb[bj], acc2[ai][bj], 0, 0, 0);
    }

    float4 b2v[4];
    #pragma unroll
    for (int ai = 0; ai < 4; ++ai)
        b2v[ai] = *(const float4*)(b2 + wcc * 64 + ai * 16 + lk * 4);

    __syncthreads();   // all mm2 reads of e1 done; safe to overwrite with out-tile

    // ---- write bf16 out-tile to LDS ----
    #pragma unroll
    for (int ai = 0; ai < 4; ++ai)
        #pragma unroll
        for (int bj = 0; bj < 2; ++bj) {
            int rloc = wr * 32 + bj * 16 + lr;
            int colb = wcc * 64 + ai * 16 + lk * 4;
            ushort4 pk;
            pk.x = f2bf(silu_f(acc2[ai][bj][0] + b2v[ai].x));
            pk.y = f2bf(silu_f(acc2[ai][bj][1] + b2v[ai].y));
            pk.z = f2bf(silu_f(acc2[ai][bj][2] + b2v[ai].z));
            pk.w = f2bf(silu_f(acc2[ai][bj][3] + b2v[ai].w));
            *(ushort4*)(&e1[rloc * ESTRIDE + colb]) = pk;
        }
    __syncthreads();

    // ---- coalesced row scatter: nontemporal, keep P12 in L2/L3 ----
    {
        int rr = tid >> 5;          // 0..7
        int cl = tid & 31;          // 32 lanes cover 128 cols as f32x4
        #pragma unroll
        for (int p = 0; p < 8; ++p) {
            int r = p * 8 + rr;
            int e = sE[r];
            ushort4 pk = *(ushort4*)(&e1[r * ESTRIDE + cl * 4]);
            f32x4 o;
            o[0] = bf2f(pk.x); o[1] = bf2f(pk.y); o[2] = bf2f(pk.z); o[3] = bf2f(pk.w);
            __builtin_nontemporal_store(o, (f32x4*)(&out_edge[(size_t)e * H + cl * 4]));
        }
    }

    // ---- segmented reduction over dst runs -> sums (2 cols x 16 rows/thread) ----
    {
        int cp = (tid & 63) * 2;        // column pair
        int r0 = (tid >> 6) * 16;       // row chunk (4 x 16 = 64 rows)
        float a0 = 0.0f, a1 = 0.0f;
        int curn = sDst[r0];
        for (int r = r0; r < r0 + 16; ++r) {
            int n = sDst[r];
            if (n != curn) {
                atomicAdd(&sums[(size_t)curn * H + cp], a0);
                atomicAdd(&sums[(size_t)curn * H + cp + 1], a1);
                a0 = a1 = 0.0f;
                curn = n;
            }
            unsigned int u = *(const unsigned int*)(&e1[r * ESTRIDE + cp]);
            a0 += bf2f((unsigned short)(u & 0xffffu));
            a1 += bf2f((unsigned short)(u >> 16));
        }
        atomicAdd(&sums[(size_t)curn * H + cp], a0);
        atomicAdd(&sums[(size_t)curn * H + cp + 1], a1);
    }
}

// ---- node kernel: agg = sums/deg computed during staging ----
__global__ __launch_bounds__(256) void node_kernel(
    const float* __restrict__ nf, const float* __restrict__ sums,
    const int* __restrict__ cnt_i,
    const unsigned short* __restrict__ W3T, const float* __restrict__ b3,
    const unsigned short* __restrict__ W4T, const float* __restrict__ b4,
    float* __restrict__ out0)
{
    __shared__ unsigned short x_lds[64 * NSTRIDE];
    int tid = threadIdx.x;
    int nb = blockIdx.x * 64;

    // cols 0..127: nf (fp32 -> bf16)
    #pragma unroll
    for (int p = 0; p < 8; ++p) {
        int idx = p * 256 + tid;
        int n = idx >> 5, c = idx & 31;
        int node = nb + n; if (node >= NN) node = NN - 1;
        float4 v = *(const float4*)(nf + (size_t)node * H + c * 4);
        ushort4 o;
        o.x = f2bf(v.x); o.y = f2bf(v.y); o.z = f2bf(v.z); o.w = f2bf(v.w);
        *(ushort4*)(&x_lds[n * NSTRIDE + c * 4]) = o;
    }
    // cols 128..255: agg = sums/max(deg,1)
    #pragma unroll
    for (int p = 0; p < 8; ++p) {
        int idx = p * 256 + tid;
        int n = idx >> 5, c = idx & 31;
        int node = nb + n; if (node >= NN) node = NN - 1;
        float4 s = *(const float4*)(sums + (size_t)node * H + c * 4);
        float inv = 1.0f / fmaxf((float)cnt_i[node], 1.0f);
        ushort4 o;
        o.x = f2bf(s.x * inv); o.y = f2bf(s.y * inv);
        o.z = f2bf(s.z * inv); o.w = f2bf(s.w * inv);
        *(ushort4*)(&x_lds[n * NSTRIDE + 128 + c * 4]) = o;
    }
    __syncthreads();

    int wid = tid >> 6, lane = tid & 63;
    int wr = wid >> 1, wc = wid & 1;
    int lr = lane & 15, lk = lane >> 4;

    f32x4 acc[2][4];
    #pragma unroll
    for (int m = 0; m < 2; ++m)
        #pragma unroll
        for (int n = 0; n < 4; ++n) acc[m][n] = (f32x4){0.f, 0.f, 0.f, 0.f};

    #pragma unroll
    for (int ks = 0; ks < 8; ++ks) {
        bhalf8 a[2], b[4];
        #pragma unroll
        for (int m = 0; m < 2; ++m)
            a[m] = *(const bhalf8*)(&x_lds[(wr * 32 + m * 16 + lr) * NSTRIDE + ks * 32 + lk * 8]);
        #pragma unroll
        for (int n = 0; n < 4; ++n)
            b[n] = *(const bhalf8*)(W3T + (size_t)(wc * 64 + n * 16 + lr) * K3 + ks * 32 + lk * 8);
        #pragma unroll
        for (int m = 0; m < 2; ++m)
            #pragma unroll
            for (int n = 0; n < 4; ++n)
                acc[m][n] = __builtin_amdgcn_mfma_f32_16x16x32_bf16(a[m], b[n], acc[m][n], 0, 0, 0);
    }

    float bn3[4];
    #pragma unroll
    for (int n = 0; n < 4; ++n) bn3[n] = b3[wc * 64 + n * 16 + lr];

    __syncthreads();
    unsigned short* m_lds = x_lds;
    #pragma unroll
    for (int m = 0; m < 2; ++m)
        #pragma unroll
        for (int n = 0; n < 4; ++n)
            #pragma unroll
            for (int j = 0; j < 4; ++j) {
                int row = wr * 32 + m * 16 + lk * 4 + j;
                int col = wc * 64 + n * 16 + lr;
                m_lds[row * ESTRIDE + col] = f2bf(silu_f(acc[m][n][j] + bn3[n]));
            }
    __syncthreads();

    f32x4 acc2[2][4];
    #pragma unroll
    for (int m = 0; m < 2; ++m)
        #pragma unroll
        for (int n = 0; n < 4; ++n) acc2[m][n] = (f32x4){0.f, 0.f, 0.f, 0.f};

    #pragma unroll
    for (int ks = 0; ks < 4; ++ks) {
        bhalf8 a[2], b[4];
        #pragma unroll
        for (int m = 0; m < 2; ++m)
            a[m] = *(const bhalf8*)(&m_lds[(wr * 32 + m * 16 + lr) * ESTRIDE + ks * 32 + lk * 8]);
        #pragma unroll
        for (int n = 0; n < 4; ++n)
            b[n] = *(const bhalf8*)(W4T + (size_t)(wc * 64 + n * 16 + lr) * H + ks * 32 + lk * 8);
        #pragma unroll
        for (int m = 0; m < 2; ++m)
            #pragma unroll
            for (int n = 0; n < 4; ++n)
                acc2[m][n] = __builtin_amdgcn_mfma_f32_16x16x32_bf16(a[m], b[n], acc2[m][n], 0, 0, 0);
    }

    float bn4[4];
    #pragma unroll
    for (int n = 0; n < 4; ++n) bn4[n] = b4[wc * 64 + n * 16 + lr];

    #pragma unroll
    for (int m = 0; m < 2; ++m)
        #pragma unroll
        for (int n = 0; n < 4; ++n)
            #pragma unroll
            for (int j = 0; j < 4; ++j) {
                int row = wr * 32 + m * 16 + lk * 4 + j;
                int col = wc * 64 + n * 16 + lr;
                int node = nb + row;
                if (node < NN) {
                    float base = nf[(size_t)node * H + col];
                    float o = base + silu_f(acc2[m][n][j] + bn4[n]);
                    __builtin_nontemporal_store(o, &out0[(size_t)node * H + col]);
                }
            }
}

extern "C" void kernel_launch(void* const* d_in, const int* in_sizes, int n_in,
                              void* d_out, int out_size, void* d_ws, size_t ws_size,
                              hipStream_t stream) {
    const float* nf  = (const float*)d_in[0];
    const float* lat = (const float*)d_in[2];
    const float* fd  = (const float*)d_in[3];
    const float* W1  = (const float*)d_in[4];
    const float* b1  = (const float*)d_in[5];
    const float* W2  = (const float*)d_in[6];
    const float* b2  = (const float*)d_in[7];
    const float* W3  = (const float*)d_in[8];
    const float* b3  = (const float*)d_in[9];
    const float* W4  = (const float*)d_in[10];
    const float* b4  = (const float*)d_in[11];
    const int* ei    = (const int*)d_in[12];
    const int* e2g   = (const int*)d_in[13];

    float* out0     = (float*)d_out;
    float* out_edge = (float*)d_out + (size_t)NN * H;

    char* ws = (char*)d_ws;
    size_t off = 0;
    float* sums = (float*)(ws + off);                   off += (size_t)NN * H * 4;     // 25.6 MB (zeroed)
    int* cnt_i      = (int*)(ws + off);                 off += (size_t)NB * 256 * 4;   // (zeroed)
    int* fill       = (int*)(ws + off);                 off += (size_t)NB * 256 * 4;   // (zeroed)
    int* row_start  = (int*)(ws + off);                 off += (size_t)NB * 256 * 4;
    int* eidx       = (int*)(ws + off);                 off += (size_t)EE * 4;         // 3.2 MB
    unsigned short* P12  = (unsigned short*)(ws + off); off += (size_t)NN * 256 * 2;   // 25.6 MB
    unsigned short* W12T = (unsigned short*)(ws + off); off += (size_t)256 * H * 2;    // 64 KB
    unsigned short* W2T  = (unsigned short*)(ws + off); off += (size_t)H * H * 2;
    unsigned short* W3T  = (unsigned short*)(ws + off); off += (size_t)H * K3 * 2;
    unsigned short* W4T  = (unsigned short*)(ws + off); off += (size_t)H * H * 2;
    unsigned short* Qb   = (unsigned short*)(ws + off); off += (size_t)GG * H * 2;     // 64 KB
    const float* W1fd = W1 + (size_t)265 * H;   // fd rows of W1, used in-place

    // zero sums + cnt_i + fill (adjacent, 16B-aligned sizes) with full-grid kernel
    int n16 = (int)(((size_t)NN * H * 4 + (size_t)NB * 256 * 4 * 2) / 16);
    zero_kernel<<<2048, 256, 0, stream>>>((uint4*)sums, n16);

    prep_kernel<<<512 + (EE + 255) / 256, 256, 0, stream>>>(
        W1, b1, W2, W3, W4, lat, ei, W12T, W2T, W3T, W4T, Qb, cnt_i);
    p12_kernel<<<(NN + 63) / 64, 256, 0, stream>>>(nf, W12T, P12);

    scan_kernel<<<1, 1024, 0, stream>>>(cnt_i, row_start);
    scatter_kernel<<<(EE + 255) / 256, 256, 0, stream>>>(ei, row_start, fill, eidx);

    edge_kernel<<<NWG_E, 256, 0, stream>>>(P12, Qb, fd, W1fd, W2T, b2,
                                           ei, e2g, eidx, out_edge, sums);
    node_kernel<<<(NN + 63) / 64, 256, 0, stream>>>(nf, sums, cnt_i, W3T, b3, W4T, b4, out0);
}

// Round 15
// 354.581 us; speedup vs baseline: 1.0521x; 1.0521x over previous
//
#include <hip/hip_runtime.h>
#include <hip/hip_bf16.h>
#include <math.h>

#define H  128
#define NN 50000
#define EE 800000
#define GG 256
#define NB 196          // ceil(NN/256)

#define K3 256
#define NSTRIDE 264     // node x-tile LDS row stride
#define ESTRIDE 136     // hidden tile LDS row stride
#define PSTRIDE 136     // p12 staging stride

typedef __attribute__((ext_vector_type(8))) short bhalf8;
typedef __attribute__((ext_vector_type(4))) float f32x4;

__device__ __forceinline__ float silu_f(float x) {
    return x * __builtin_amdgcn_rcpf(1.0f + exp2f(x * -1.442695041f));
}

// fp32 -> bf16 round-to-nearest-even (branchless integer RNE — faster than
// library cast here; R14 A/B showed the __float2bfloat16 path regresses)
__device__ __forceinline__ unsigned short f2bf(float x) {
    unsigned int u = __float_as_uint(x);
    unsigned int r = 0x7fffu + ((u >> 16) & 1u);
    return (unsigned short)((u + r) >> 16);
}

// bf16 bits -> fp32
__device__ __forceinline__ float bf2f(unsigned short s) {
    return __uint_as_float(((unsigned int)s) << 16);
}

// ---- fast zero (runtime memset node fills at ~100 GB/s; this runs full-grid) ----
__global__ void zero_kernel(uint4* __restrict__ p, int n16) {
    uint4 z; z.x = z.y = z.z = z.w = 0;
    for (int i = blockIdx.x * blockDim.x + threadIdx.x; i < n16; i += gridDim.x * blockDim.x)
        p[i] = z;
}

// ---- merged prep kernel: W2T/W4T/W3T/W12T/Qb + degree count ----
__global__ __launch_bounds__(256) void prep_kernel(
    const float* __restrict__ W1, const float* __restrict__ b1,
    const float* __restrict__ W2, const float* __restrict__ W3,
    const float* __restrict__ W4, const float* __restrict__ lat,
    const int* __restrict__ ei,
    unsigned short* __restrict__ W12T, unsigned short* __restrict__ W2T,
    unsigned short* __restrict__ W3T, unsigned short* __restrict__ W4T,
    unsigned short* __restrict__ Qb, int* __restrict__ cnt_i)
{
    int bid = blockIdx.x, tid = threadIdx.x;
    if (bid < 64) {
        int c = bid * 2 + (tid >> 7), k = tid & 127;
        W2T[(size_t)c * H + k] = f2bf(W2[(size_t)k * H + c]);
    } else if (bid < 128) {
        int c = (bid - 64) * 2 + (tid >> 7), k = tid & 127;
        W4T[(size_t)c * H + k] = f2bf(W4[(size_t)k * H + c]);
    } else if (bid < 256) {
        int c = bid - 128, k = tid;
        W3T[(size_t)c * K3 + k] = f2bf(W3[(size_t)k * H + c]);
    } else if (bid < 384) {
        int j = (bid - 256) * 2 + (tid >> 7), k = tid & 127;
        float v = (j < 128) ? W1[(size_t)k * H + j] : W1[(size_t)(128 + k) * H + (j - 128)];
        W12T[(size_t)j * H + k] = f2bf(v);
    } else if (bid < 512) {
        int g = (bid - 384) * 2 + (tid >> 7), c = tid & 127;
        const float* L = lat + g * 9;
        float q = b1[c];
        #pragma unroll
        for (int i = 0; i < 3; ++i)
            #pragma unroll
            for (int k = 0; k < 3; ++k) {
                float ip = L[i*3+0]*L[k*3+0] + L[i*3+1]*L[k*3+1] + L[i*3+2]*L[k*3+2];
                q += ip * W1[(size_t)(256 + i * 3 + k) * H + c];
            }
        Qb[(size_t)g * H + c] = f2bf(q);
    } else {
        int e = (bid - 512) * 256 + tid;
        if (e < EE) atomicAdd(&cnt_i[ei[EE + e]], 1);
    }
}

// P12[n][0:128] = nf[n] @ W1a ; P12[n][128:256] = nf[n] @ W1b  (bf16 out)
__global__ __launch_bounds__(256) void p12_kernel(
    const float* __restrict__ nf, const unsigned short* __restrict__ W12T,
    unsigned short* __restrict__ P12)
{
    __shared__ unsigned short x_lds[64 * PSTRIDE];
    int tid = threadIdx.x;
    int nb = blockIdx.x * 64;

    #pragma unroll
    for (int p = 0; p < 8; ++p) {
        int idx = p * 256 + tid;
        int n = idx >> 5, c = idx & 31;
        int node = nb + n; if (node >= NN) node = NN - 1;
        float4 v = *(const float4*)(nf + (size_t)node * H + c * 4);
        ushort4 o;
        o.x = f2bf(v.x); o.y = f2bf(v.y); o.z = f2bf(v.z); o.w = f2bf(v.w);
        *(ushort4*)(&x_lds[n * PSTRIDE + c * 4]) = o;
    }
    __syncthreads();

    int wid = tid >> 6, lane = tid & 63;
    int wr = wid & 1, wc = wid >> 1;       // rows wr*32.., cols wc*128..
    int lr = lane & 15, lk = lane >> 4;

    f32x4 acc[2][8];
    #pragma unroll
    for (int m = 0; m < 2; ++m)
        #pragma unroll
        for (int n = 0; n < 8; ++n) acc[m][n] = (f32x4){0.f, 0.f, 0.f, 0.f};

    #pragma unroll
    for (int ks = 0; ks < 4; ++ks) {
        bhalf8 a[2], b[8];
        #pragma unroll
        for (int m = 0; m < 2; ++m)
            a[m] = *(const bhalf8*)(&x_lds[(wr * 32 + m * 16 + lr) * PSTRIDE + ks * 32 + lk * 8]);
        #pragma unroll
        for (int n = 0; n < 8; ++n)
            b[n] = *(const bhalf8*)(W12T + (size_t)(wc * 128 + n * 16 + lr) * H + ks * 32 + lk * 8);
        #pragma unroll
        for (int m = 0; m < 2; ++m)
            #pragma unroll
            for (int n = 0; n < 8; ++n)
                acc[m][n] = __builtin_amdgcn_mfma_f32_16x16x32_bf16(a[m], b[n], acc[m][n], 0, 0, 0);
    }

    #pragma unroll
    for (int m = 0; m < 2; ++m)
        #pragma unroll
        for (int n = 0; n < 8; ++n)
            #pragma unroll
            for (int j = 0; j < 4; ++j) {
                int row = wr * 32 + m * 16 + lk * 4 + j;
                int col = wc * 128 + n * 16 + lr;
                int node = nb + row;
                if (node < NN) P12[(size_t)node * 256 + col] = f2bf(acc[m][n][j]);
            }
}

// ---- CSR build ----

__global__ void scan1_kernel(const int* __restrict__ cnt_i, int* __restrict__ bsum) {
    __shared__ int red[256];
    int b = blockIdx.x, t = threadIdx.x;
    int n = b * 256 + t;
    red[t] = (n < NN) ? cnt_i[n] : 0;
    __syncthreads();
    for (int s = 128; s > 0; s >>= 1) {
        if (t < s) red[t] += red[t + s];
        __syncthreads();
    }
    if (t == 0) bsum[b] = red[0];
}

__global__ void scan2_kernel(const int* __restrict__ bsum, int* __restrict__ bbase) {
    __shared__ int tmp[256];
    int t = threadIdx.x;
    int c = (t < NB) ? bsum[t] : 0;
    tmp[t] = c;
    __syncthreads();
    for (int s = 1; s < 256; s <<= 1) {
        int u = (t >= s) ? tmp[t - s] : 0;
        __syncthreads();
        tmp[t] += u;
        __syncthreads();
    }
    if (t < NB) bbase[t] = tmp[t] - c;   // exclusive
}

__global__ void scan3_kernel(const int* __restrict__ cnt_i, const int* __restrict__ bbase,
                             int* __restrict__ row_start) {
    __shared__ int tmp[256];
    int b = blockIdx.x, t = threadIdx.x;
    int n = b * 256 + t;
    int c = (n < NN) ? cnt_i[n] : 0;
    tmp[t] = c;
    __syncthreads();
    for (int s = 1; s < 256; s <<= 1) {
        int u = (t >= s) ? tmp[t - s] : 0;
        __syncthreads();
        tmp[t] += u;
        __syncthreads();
    }
    if (n < NN) row_start[n] = bbase[b] + tmp[t] - c;   // exclusive
}

__global__ void scatter_kernel(const int* __restrict__ ei, const int* __restrict__ row_start,
                               int* __restrict__ fill, int* __restrict__ eidx) {
    int e = blockIdx.x * blockDim.x + threadIdx.x;
    if (e < EE) {
        int d = ei[EE + e];
        int pos = row_start[d] + atomicAdd(&fill[d], 1);
        eidx[pos] = e;
    }
}

// ---- edge kernel v9: 64-edge tiles, 256 threads, 5 blocks/CU for gather overlap ----
__global__ __launch_bounds__(256, 5) void edge_kernel(
    const unsigned short* __restrict__ P12, const unsigned short* __restrict__ Qb,
    const float* __restrict__ fdg, const float* __restrict__ W1fd,
    const unsigned short* __restrict__ W2T, const float* __restrict__ b2,
    const int* __restrict__ ei, const int* __restrict__ e2g,
    const int* __restrict__ eidx,
    float* __restrict__ out_edge, float* __restrict__ sums)
{
    __shared__ unsigned short e1[64 * ESTRIDE];   // 17.4 KB; reused as out-tile (bf16)
    __shared__ int sE[64], sSrc[64], sDst[64], sG[64];
    __shared__ float sFd[64 * 3];

    int tid = threadIdx.x;
    int eb = blockIdx.x * 64;

    if (tid < 64) sE[tid] = eidx[eb + tid];
    __syncthreads();
    if (tid < 64) {
        sSrc[tid] = ei[sE[tid]];
    } else if (tid < 128) {
        sDst[tid - 64] = ei[EE + sE[tid - 64]];
    } else if (tid < 192) {
        sG[tid - 128] = e2g[sE[tid - 128]];
    } else {
        int r = tid - 192;
        int e = sE[r];
        sFd[r * 3 + 0] = fdg[(size_t)e * 3 + 0];
        sFd[r * 3 + 1] = fdg[(size_t)e * 3 + 1];
        sFd[r * 3 + 2] = fdg[(size_t)e * 3 + 2];
    }
    __syncthreads();

    int c = tid & 15;
    // per-lane W1_fd columns (3 rows x 8 cols), L1-cached
    float4 wf[3][2];
    #pragma unroll
    for (int k = 0; k < 3; ++k)
        #pragma unroll
        for (int h = 0; h < 2; ++h)
            wf[k][h] = *(const float4*)(W1fd + k * H + c * 8 + h * 4);

    // ---- prefetch all P12 gathers (8 independent 16B loads in flight) ----
    uint4 P1v[4], P2v[4];
    #pragma unroll
    for (int p = 0; p < 4; ++p) {
        int r = p * 16 + (tid >> 4);
        P1v[p] = *(const uint4*)(P12 + (size_t)sSrc[r] * 256 + c * 8);
        P2v[p] = *(const uint4*)(P12 + (size_t)sDst[r] * 256 + 128 + c * 8);
    }

    // ---- build e1[64][128] (bf16): 4 rows per thread ----
    #pragma unroll
    for (int p = 0; p < 4; ++p) {
        int r = p * 16 + (tid >> 4);
        int g = sG[r];
        bhalf8 p1 = *(const bhalf8*)(&P1v[p]);
        bhalf8 p2 = *(const bhalf8*)(&P2v[p]);
        bhalf8 qv = *(const bhalf8*)(Qb + (size_t)g * H + c * 8);
        float f0 = sFd[r * 3 + 0], f1 = sFd[r * 3 + 1], f2v = sFd[r * 3 + 2];
        unsigned int w[4];
        #pragma unroll
        for (int jj = 0; jj < 4; ++jj) {
            unsigned int lo = 0, hi = 0;
            #pragma unroll
            for (int half = 0; half < 2; ++half) {
                int j = jj * 2 + half;
                const float* wfp = (const float*)&wf[0][0];
                float wv0 = wfp[j];
                float wv1 = wfp[8 + j];
                float wv2 = wfp[16 + j];
                float v = bf2f((unsigned short)p1[j]) + bf2f((unsigned short)p2[j])
                        + bf2f((unsigned short)qv[j])
                        + f0 * wv0 + f1 * wv1 + f2v * wv2;
                unsigned int us = f2bf(silu_f(v));
                if (half == 0) lo = us; else hi = us;
            }
            w[jj] = lo | (hi << 16);
        }
        uint4 pk; pk.x = w[0]; pk.y = w[1]; pk.z = w[2]; pk.w = w[3];
        *(uint4*)(&e1[r * ESTRIDE + c * 8]) = pk;
    }
    __syncthreads();

    // ---- mm2: 4 waves, each 32 rows x 64 cols ----
    int wid = tid >> 6, lane = tid & 63;
    int wr = wid >> 1, wcc = wid & 1;   // rows wr*32.., cols wcc*64..
    int lr = lane & 15, lk = lane >> 4;

    f32x4 acc2[4][2];
    #pragma unroll
    for (int a = 0; a < 4; ++a)
        #pragma unroll
        for (int b = 0; b < 2; ++b) acc2[a][b] = (f32x4){0.f, 0.f, 0.f, 0.f};

    #pragma unroll
    for (int ks = 0; ks < 4; ++ks) {
        bhalf8 wa[4], xb[2];
        #pragma unroll
        for (int ai = 0; ai < 4; ++ai)
            wa[ai] = *(const bhalf8*)(W2T + (size_t)(wcc * 64 + ai * 16 + lr) * H + ks * 32 + lk * 8);
        #pragma unroll
        for (int bj = 0; bj < 2; ++bj)
            xb[bj] = *(const bhalf8*)(&e1[(wr * 32 + bj * 16 + lr) * ESTRIDE + ks * 32 + lk * 8]);
        #pragma unroll
        for (int ai = 0; ai < 4; ++ai)
            #pragma unroll
            for (int bj = 0; bj < 2; ++bj)
                acc2[ai][bj] = __builtin_amdgcn_mfma_f32_16x16x32_bf16(wa[ai], xb[bj], acc2[ai][bj], 0, 0, 0);
    }

    float4 b2v[4];
    #pragma unroll
    for (int ai = 0; ai < 4; ++ai)
        b2v[ai] = *(const float4*)(b2 + wcc * 64 + ai * 16 + lk * 4);

    __syncthreads();   // all mm2 reads of e1 done; safe to overwrite with out-tile

    // ---- write bf16 out-tile to LDS ----
    #pragma unroll
    for (int ai = 0; ai < 4; ++ai)
        #pragma unroll
        for (int bj = 0; bj < 2; ++bj) {
            int rloc = wr * 32 + bj * 16 + lr;
            int colb = wcc * 64 + ai * 16 + lk * 4;
            ushort4 pk;
            pk.x = f2bf(silu_f(acc2[ai][bj][0] + b2v[ai].x));
            pk.y = f2bf(silu_f(acc2[ai][bj][1] + b2v[ai].y));
            pk.z = f2bf(silu_f(acc2[ai][bj][2] + b2v[ai].z));
            pk.w = f2bf(silu_f(acc2[ai][bj][3] + b2v[ai].w));
            *(ushort4*)(&e1[rloc * ESTRIDE + colb]) = pk;
        }
    __syncthreads();

    // ---- coalesced row scatter: nontemporal, keep P12 in L2/L3 ----
    {
        int rr = tid >> 5;          // 0..7
        int cl = tid & 31;          // 32 lanes cover 128 cols as f32x4
        #pragma unroll
        for (int p = 0; p < 8; ++p) {
            int r = p * 8 + rr;
            int e = sE[r];
            ushort4 pk = *(ushort4*)(&e1[r * ESTRIDE + cl * 4]);
            f32x4 o;
            o[0] = bf2f(pk.x); o[1] = bf2f(pk.y); o[2] = bf2f(pk.z); o[3] = bf2f(pk.w);
            __builtin_nontemporal_store(o, (f32x4*)(&out_edge[(size_t)e * H + cl * 4]));
        }
    }

    // ---- segmented reduction over dst runs -> sums (2 cols x 16 rows/thread) ----
    {
        int cp = (tid & 63) * 2;        // column pair
        int r0 = (tid >> 6) * 16;       // row chunk (4 x 16 = 64 rows)
        float a0 = 0.0f, a1 = 0.0f;
        int curn = sDst[r0];
        for (int r = r0; r < r0 + 16; ++r) {
            int n = sDst[r];
            if (n != curn) {
                atomicAdd(&sums[(size_t)curn * H + cp], a0);
                atomicAdd(&sums[(size_t)curn * H + cp + 1], a1);
                a0 = a1 = 0.0f;
                curn = n;
            }
            unsigned int u = *(const unsigned int*)(&e1[r * ESTRIDE + cp]);
            a0 += bf2f((unsigned short)(u & 0xffffu));
            a1 += bf2f((unsigned short)(u >> 16));
        }
        atomicAdd(&sums[(size_t)curn * H + cp], a0);
        atomicAdd(&sums[(size_t)curn * H + cp + 1], a1);
    }
}

// ---- node kernel: agg = sums/deg computed during staging ----
__global__ __launch_bounds__(256) void node_kernel(
    const float* __restrict__ nf, const float* __restrict__ sums,
    const int* __restrict__ cnt_i,
    const unsigned short* __restrict__ W3T, const float* __restrict__ b3,
    const unsigned short* __restrict__ W4T, const float* __restrict__ b4,
    float* __restrict__ out0)
{
    __shared__ unsigned short x_lds[64 * NSTRIDE];
    int tid = threadIdx.x;
    int nb = blockIdx.x * 64;

    // cols 0..127: nf (fp32 -> bf16)
    #pragma unroll
    for (int p = 0; p < 8; ++p) {
        int idx = p * 256 + tid;
        int n = idx >> 5, c = idx & 31;
        int node = nb + n; if (node >= NN) node = NN - 1;
        float4 v = *(const float4*)(nf + (size_t)node * H + c * 4);
        ushort4 o;
        o.x = f2bf(v.x); o.y = f2bf(v.y); o.z = f2bf(v.z); o.w = f2bf(v.w);
        *(ushort4*)(&x_lds[n * NSTRIDE + c * 4]) = o;
    }
    // cols 128..255: agg = sums/max(deg,1)
    #pragma unroll
    for (int p = 0; p < 8; ++p) {
        int idx = p * 256 + tid;
        int n = idx >> 5, c = idx & 31;
        int node = nb + n; if (node >= NN) node = NN - 1;
        float4 s = *(const float4*)(sums + (size_t)node * H + c * 4);
        float inv = 1.0f / fmaxf((float)cnt_i[node], 1.0f);
        ushort4 o;
        o.x = f2bf(s.x * inv); o.y = f2bf(s.y * inv);
        o.z = f2bf(s.z * inv); o.w = f2bf(s.w * inv);
        *(ushort4*)(&x_lds[n * NSTRIDE + 128 + c * 4]) = o;
    }
    __syncthreads();

    int wid = tid >> 6, lane = tid & 63;
    int wr = wid >> 1, wc = wid & 1;
    int lr = lane & 15, lk = lane >> 4;

    f32x4 acc[2][4];
    #pragma unroll
    for (int m = 0; m < 2; ++m)
        #pragma unroll
        for (int n = 0; n < 4; ++n) acc[m][n] = (f32x4){0.f, 0.f, 0.f, 0.f};

    #pragma unroll
    for (int ks = 0; ks < 8; ++ks) {
        bhalf8 a[2], b[4];
        #pragma unroll
        for (int m = 0; m < 2; ++m)
            a[m] = *(const bhalf8*)(&x_lds[(wr * 32 + m * 16 + lr) * NSTRIDE + ks * 32 + lk * 8]);
        #pragma unroll
        for (int n = 0; n < 4; ++n)
            b[n] = *(const bhalf8*)(W3T + (size_t)(wc * 64 + n * 16 + lr) * K3 + ks * 32 + lk * 8);
        #pragma unroll
        for (int m = 0; m < 2; ++m)
            #pragma unroll
            for (int n = 0; n < 4; ++n)
                acc[m][n] = __builtin_amdgcn_mfma_f32_16x16x32_bf16(a[m], b[n], acc[m][n], 0, 0, 0);
    }

    float bn3[4];
    #pragma unroll
    for (int n = 0; n < 4; ++n) bn3[n] = b3[wc * 64 + n * 16 + lr];

    __syncthreads();
    unsigned short* m_lds = x_lds;
    #pragma unroll
    for (int m = 0; m < 2; ++m)
        #pragma unroll
        for (int n = 0; n < 4; ++n)
            #pragma unroll
            for (int j = 0; j < 4; ++j) {
                int row = wr * 32 + m * 16 + lk * 4 + j;
                int col = wc * 64 + n * 16 + lr;
                m_lds[row * ESTRIDE + col] = f2bf(silu_f(acc[m][n][j] + bn3[n]));
            }
    __syncthreads();

    f32x4 acc2[2][4];
    #pragma unroll
    for (int m = 0; m < 2; ++m)
        #pragma unroll
        for (int n = 0; n < 4; ++n) acc2[m][n] = (f32x4){0.f, 0.f, 0.f, 0.f};

    #pragma unroll
    for (int ks = 0; ks < 4; ++ks) {
        bhalf8 a[2], b[4];
        #pragma unroll
        for (int m = 0; m < 2; ++m)
            a[m] = *(const bhalf8*)(&m_lds[(wr * 32 + m * 16 + lr) * ESTRIDE + ks * 32 + lk * 8]);
        #pragma unroll
        for (int n = 0; n < 4; ++n)
            b[n] = *(const bhalf8*)(W4T + (size_t)(wc * 64 + n * 16 + lr) * H + ks * 32 + lk * 8);
        #pragma unroll
        for (int m = 0; m < 2; ++m)
            #pragma unroll
            for (int n = 0; n < 4; ++n)
                acc2[m][n] = __builtin_amdgcn_mfma_f32_16x16x32_bf16(a[m], b[n], acc2[m][n], 0, 0, 0);
    }

    float bn4[4];
    #pragma unroll
    for (int n = 0; n < 4; ++n) bn4[n] = b4[wc * 64 + n * 16 + lr];

    #pragma unroll
    for (int m = 0; m < 2; ++m)
        #pragma unroll
        for (int n = 0; n < 4; ++n)
            #pragma unroll
            for (int j = 0; j < 4; ++j) {
                int row = wr * 32 + m * 16 + lk * 4 + j;
                int col = wc * 64 + n * 16 + lr;
                int node = nb + row;
                if (node < NN) {
                    float base = nf[(size_t)node * H + col];
                    float o = base + silu_f(acc2[m][n][j] + bn4[n]);
                    __builtin_nontemporal_store(o, &out0[(size_t)node * H + col]);
                }
            }
}

extern "C" void kernel_launch(void* const* d_in, const int* in_sizes, int n_in,
                              void* d_out, int out_size, void* d_ws, size_t ws_size,
                              hipStream_t stream) {
    const float* nf  = (const float*)d_in[0];
    const float* lat = (const float*)d_in[2];
    const float* fd  = (const float*)d_in[3];
    const float* W1  = (const float*)d_in[4];
    const float* b1  = (const float*)d_in[5];
    const float* W2  = (const float*)d_in[6];
    const float* b2  = (const float*)d_in[7];
    const float* W3  = (const float*)d_in[8];
    const float* b3  = (const float*)d_in[9];
    const float* W4  = (const float*)d_in[10];
    const float* b4  = (const float*)d_in[11];
    const int* ei    = (const int*)d_in[12];
    const int* e2g   = (const int*)d_in[13];

    float* out0     = (float*)d_out;
    float* out_edge = (float*)d_out + (size_t)NN * H;

    char* ws = (char*)d_ws;
    size_t off = 0;
    float* sums = (float*)(ws + off);                   off += (size_t)NN * H * 4;     // 25.6 MB (zeroed)
    int* cnt_i      = (int*)(ws + off);                 off += (size_t)NB * 256 * 4;   // (zeroed)
    int* fill       = (int*)(ws + off);                 off += (size_t)NB * 256 * 4;   // (zeroed)
    int* row_start  = (int*)(ws + off);                 off += (size_t)NB * 256 * 4;
    int* bsum       = (int*)(ws + off);                 off += 256 * 4;
    int* bbase      = (int*)(ws + off);                 off += 256 * 4;
    int* eidx       = (int*)(ws + off);                 off += (size_t)EE * 4;         // 3.2 MB
    unsigned short* P12  = (unsigned short*)(ws + off); off += (size_t)NN * 256 * 2;   // 25.6 MB
    unsigned short* W12T = (unsigned short*)(ws + off); off += (size_t)256 * H * 2;    // 64 KB
    unsigned short* W2T  = (unsigned short*)(ws + off); off += (size_t)H * H * 2;
    unsigned short* W3T  = (unsigned short*)(ws + off); off += (size_t)H * K3 * 2;
    unsigned short* W4T  = (unsigned short*)(ws + off); off += (size_t)H * H * 2;
    unsigned short* Qb   = (unsigned short*)(ws + off); off += (size_t)GG * H * 2;     // 64 KB
    const float* W1fd = W1 + (size_t)265 * H;   // fd rows of W1, used in-place

    // zero sums + cnt_i + fill (adjacent, 16B-aligned sizes) with full-grid kernel
    int n16 = (int)(((size_t)NN * H * 4 + (size_t)NB * 256 * 4 * 2) / 16);
    zero_kernel<<<2048, 256, 0, stream>>>((uint4*)sums, n16);

    prep_kernel<<<512 + (EE + 255) / 256, 256, 0, stream>>>(
        W1, b1, W2, W3, W4, lat, ei, W12T, W2T, W3T, W4T, Qb, cnt_i);
    p12_kernel<<<(NN + 63) / 64, 256, 0, stream>>>(nf, W12T, P12);

    scan1_kernel<<<NB, 256, 0, stream>>>(cnt_i, bsum);
    scan2_kernel<<<1, 256, 0, stream>>>(bsum, bbase);
    scan3_kernel<<<NB, 256, 0, stream>>>(cnt_i, bbase, row_start);
    scatter_kernel<<<(EE + 255) / 256, 256, 0, stream>>>(ei, row_start, fill, eidx);

    edge_kernel<<<EE / 64, 256, 0, stream>>>(P12, Qb, fd, W1fd, W2T, b2,
                                             ei, e2g, eidx, out_edge, sums);
    node_kernel<<<(NN + 63) / 64, 256, 0, stream>>>(nf, sums, cnt_i, W3T, b3, W4T, b4, out0);
}